// Round 3
// baseline (282.754 us; speedup 1.0000x reference)
//
#include <hip/hip_runtime.h>
#include <math.h>

// log(2*pi) + 1
#define LOG_2PI_PLUS_1 2.8378770664093454835606594728112

// ws layout (16 B, zeroed by hipMemsetAsync each launch):
//   ((float*)ws)[0] : fp32 accumulator for sum of logs
//   ((uint*)ws)[1]  : ticket counter for last-block-done
//
// Precision note: total ≈ 3.1e7 and out = log1p(total), so d(out)/d(sumD) ≈
// 1.6e-8 — the 0.345 output threshold allows ~2e7 absolute error in sumD.
// fp32 accumulation (per-thread 16 terms, tree reduce, 2048 fp32 atomics at
// ~3e7 magnitude, ulp≈2) gives error ~1e3-1e4: 3+ orders inside tolerance.
// This removes every v_add_f64/v_cvt_f64 from the hot loop.
//
// Memory layout: each block owns a CONTIGUOUS chunk (4096 float4 = 64 KiB),
// swept block-stride with a 4-deep unroll: 4 independent coalesced 1-KiB
// wave-loads in flight, sequential DRAM streams, per-XCD L2 locality.
__global__ __launch_bounds__(256) void fused_masked_logsum_kernel(
    const float* __restrict__ x, long long n, float* __restrict__ ws,
    float* __restrict__ out, double mn_half, unsigned int nblocks) {
  const long long n4 = n >> 2;
  const float4* __restrict__ x4 = (const float4*)x;
  const long long per_block = (n4 + nblocks - 1) / nblocks;
  const long long begin = (long long)blockIdx.x * per_block;
  const long long end = (begin + per_block < n4) ? (begin + per_block) : n4;
  const int bs = blockDim.x;  // 256

  float acc = 0.0f;
  long long i = begin + threadIdx.x;
  // 4-deep unroll: 4 independent loads issued before any dependent use.
  for (; i + 3LL * bs < end; i += 4LL * bs) {
    float4 a = x4[i];
    float4 b = x4[i + bs];
    float4 c = x4[i + 2LL * bs];
    float4 d = x4[i + 3LL * bs];
    float sa = 0.0f, sb = 0.0f, sc = 0.0f, sd = 0.0f;
    sa += (a.x != 0.0f) ? __logf(a.x) : 0.0f;
    sa += (a.y != 0.0f) ? __logf(a.y) : 0.0f;
    sa += (a.z != 0.0f) ? __logf(a.z) : 0.0f;
    sa += (a.w != 0.0f) ? __logf(a.w) : 0.0f;
    sb += (b.x != 0.0f) ? __logf(b.x) : 0.0f;
    sb += (b.y != 0.0f) ? __logf(b.y) : 0.0f;
    sb += (b.z != 0.0f) ? __logf(b.z) : 0.0f;
    sb += (b.w != 0.0f) ? __logf(b.w) : 0.0f;
    sc += (c.x != 0.0f) ? __logf(c.x) : 0.0f;
    sc += (c.y != 0.0f) ? __logf(c.y) : 0.0f;
    sc += (c.z != 0.0f) ? __logf(c.z) : 0.0f;
    sc += (c.w != 0.0f) ? __logf(c.w) : 0.0f;
    sd += (d.x != 0.0f) ? __logf(d.x) : 0.0f;
    sd += (d.y != 0.0f) ? __logf(d.y) : 0.0f;
    sd += (d.z != 0.0f) ? __logf(d.z) : 0.0f;
    sd += (d.w != 0.0f) ? __logf(d.w) : 0.0f;
    acc += (sa + sb) + (sc + sd);
  }
  for (; i < end; i += bs) {
    float4 a = x4[i];
    float sa = 0.0f;
    sa += (a.x != 0.0f) ? __logf(a.x) : 0.0f;
    sa += (a.y != 0.0f) ? __logf(a.y) : 0.0f;
    sa += (a.z != 0.0f) ? __logf(a.z) : 0.0f;
    sa += (a.w != 0.0f) ? __logf(a.w) : 0.0f;
    acc += sa;
  }

  // scalar tail (n % 4) — n = 4096*8192 so never runs; kept for generality.
  if (blockIdx.x == 0 && threadIdx.x == 0) {
    for (long long j = n4 << 2; j < n; ++j) {
      float v = x[j];
      acc += (v != 0.0f) ? __logf(v) : 0.0f;
    }
  }

  // 64-lane wave butterfly (wave64!)
  #pragma unroll
  for (int off = 32; off > 0; off >>= 1) {
    acc += __shfl_down(acc, off, 64);
  }

  __shared__ float smem[4];  // 256 threads / 64 lanes = 4 waves
  const int lane = threadIdx.x & 63;
  const int wave = threadIdx.x >> 6;
  if (lane == 0) smem[wave] = acc;
  __syncthreads();

  if (threadIdx.x == 0) {
    float t = (smem[0] + smem[1]) + (smem[2] + smem[3]);
    atomicAdd(ws, t);  // device-scope fp32 HW atomic
    __threadfence();   // accumulator add visible before taking a ticket
    unsigned int* ticket = (unsigned int*)ws + 1;
    unsigned int prev = atomicAdd(ticket, 1u);
    if (prev == nblocks - 1) {
      __threadfence();
      // all 2048 partials are in; read total via atomic to defeat caching
      float sumD = atomicAdd(ws, 0.0f);
      double total = mn_half * LOG_2PI_PLUS_1 + 0.5 * (double)sumD;
      out[0] = (total > 0.0) ? (float)log1p(total) : 1.0f;
    }
  }
}

extern "C" void kernel_launch(void* const* d_in, const int* in_sizes, int n_in,
                              void* d_out, int out_size, void* d_ws, size_t ws_size,
                              hipStream_t stream) {
  const float* x = (const float*)d_in[0];
  long long n = (long long)in_sizes[0];

  // ws re-poisoned to 0xAA before every timed launch — zero acc + ticket.
  hipMemsetAsync(d_ws, 0, 16, stream);

  // 2048 blocks x 256 threads: each block owns a contiguous 64 KiB chunk
  // (16 float4/thread, exactly 4 iterations of the 4-deep unroll, no tail).
  const int block = 256;
  const unsigned int grid = 2048;
  fused_masked_logsum_kernel<<<grid, block, 0, stream>>>(
      x, n, (float*)d_ws, (float*)d_out, 0.5 * (double)n, grid);
}

// Round 4
// 202.236 us; speedup vs baseline: 1.3981x; 1.3981x over previous
//
#include <hip/hip_runtime.h>
#include <math.h>

// log(2*pi) + 1
#define LOG_2PI_PLUS_1 2.8378770664093454835606594728112

// ws layout (16 B, zeroed via hipMemsetAsync each launch):
//   ((float*)ws)[0] : fp32 accumulator for the masked log-sum
//
// LESSON (R2/R3): device-scope __threadfence() in the hot kernel forces
// per-XCD L2 writeback/invalidate (L2s are not cross-XCD coherent) —
// thousands of them destroyed streaming memory throughput (452 GB/s, 148 us).
// Fix: NO fences in the hot kernel. The kernel->kernel graph-node boundary is
// a free device-wide sync, so a separate 1-thread finalize kernel reads the
// accumulator safely (this was round 1's structure, the fast one).
//
// Precision: total ~= 3.1e7, out = log1p(total) => d(out)/d(sum) ~= 3.2e-8.
// Output threshold 0.345 allows ~1e7 absolute error in the sum; fp32
// accumulation error here is ~1e3-1e4. Safe by 3+ orders of magnitude.
__global__ __launch_bounds__(256) void masked_logsum_kernel(
    const float* __restrict__ x, long long n, float* __restrict__ ws) {
  const long long n4 = n >> 2;
  const float4* __restrict__ x4 = (const float4*)x;
  const long long tid = (long long)blockIdx.x * blockDim.x + threadIdx.x;
  const long long stride = (long long)gridDim.x * blockDim.x;

  // Round-1's empirically-fast loop: simple grid-stride, one float4 per iter,
  // coalesced 1-KiB wave loads. Let the compiler pipeline it.
  float acc = 0.0f;
  for (long long i = tid; i < n4; i += stride) {
    float4 v = x4[i];
    float s = 0.0f;
    s += (v.x != 0.0f) ? __logf(v.x) : 0.0f;
    s += (v.y != 0.0f) ? __logf(v.y) : 0.0f;
    s += (v.z != 0.0f) ? __logf(v.z) : 0.0f;
    s += (v.w != 0.0f) ? __logf(v.w) : 0.0f;
    acc += s;
  }

  // scalar tail (n % 4) — n = 4096*8192 so never runs; kept for generality.
  if (tid == 0) {
    for (long long j = n4 << 2; j < n; ++j) {
      float v = x[j];
      acc += (v != 0.0f) ? __logf(v) : 0.0f;
    }
  }

  // 64-lane wave butterfly (wave64!)
  #pragma unroll
  for (int off = 32; off > 0; off >>= 1) {
    acc += __shfl_down(acc, off, 64);
  }

  __shared__ float smem[4];  // 256 threads / 64 lanes = 4 waves
  const int lane = threadIdx.x & 63;
  const int wave = threadIdx.x >> 6;
  if (lane == 0) smem[wave] = acc;
  __syncthreads();

  if (threadIdx.x == 0) {
    float t = (smem[0] + smem[1]) + (smem[2] + smem[3]);
    atomicAdd(ws, t);  // device-scope fp32 HW atomic; NO fence needed here
  }
}

__global__ void finalize_kernel(const float* __restrict__ ws,
                                float* __restrict__ out, double mn_half) {
  double total = mn_half * LOG_2PI_PLUS_1 + 0.5 * (double)ws[0];
  out[0] = (total > 0.0) ? (float)log1p(total) : 1.0f;
}

extern "C" void kernel_launch(void* const* d_in, const int* in_sizes, int n_in,
                              void* d_out, int out_size, void* d_ws, size_t ws_size,
                              hipStream_t stream) {
  const float* x = (const float*)d_in[0];
  long long n = (long long)in_sizes[0];

  // ws is re-poisoned to 0xAA before every timed launch — zero the accumulator.
  hipMemsetAsync(d_ws, 0, 16, stream);

  // 2048 blocks x 256 threads (round-1 config): 16 float4/thread.
  const int block = 256;
  const int grid = 2048;
  masked_logsum_kernel<<<grid, block, 0, stream>>>(x, n, (float*)d_ws);
  finalize_kernel<<<1, 1, 0, stream>>>((float*)d_ws, (float*)d_out,
                                       0.5 * (double)n);
}

// Round 5
// 186.444 us; speedup vs baseline: 1.5166x; 1.0847x over previous
//
#include <hip/hip_runtime.h>
#include <math.h>

// log(2*pi) + 1
#define LOG_2PI_PLUS_1 2.8378770664093454835606594728112

#define NBLOCKS 2048

// ws layout: ws[0..NBLOCKS) floats = per-block partial sums. Every slot is
// unconditionally written by the main kernel, so the harness's 0xAA poison
// needs NO memset — one fewer graph node.
//
// LESSON (R2/R3): device-scope __threadfence() in the hot kernel wrecks the
// memory system (~+75 us). LESSON (R5 hypothesis): 2048 device-scope
// atomicAdds to ONE address serialize at a single L2 bank of the home XCD,
// mostly cross-XCD — replace with plain per-block stores + a tiny second
// reduce kernel. Kernel->kernel graph-node boundary gives visibility free.
//
// Precision: total ~= 3.1e7, out = log1p(total) => d(out)/d(sum) ~= 3.2e-8.
// Output threshold 0.345 allows ~1e7 absolute error in the log-sum; fp32
// accumulation error here is ~1e3-1e4. Safe by 3+ orders of magnitude.
__global__ __launch_bounds__(256) void masked_logsum_kernel(
    const float* __restrict__ x, long long n, float* __restrict__ partials) {
  const long long n4 = n >> 2;
  const float4* __restrict__ x4 = (const float4*)x;
  const long long tid = (long long)blockIdx.x * blockDim.x + threadIdx.x;
  const long long stride = (long long)gridDim.x * blockDim.x;

  // R1/R4's empirically-fast loop: simple grid-stride, one float4 per iter,
  // coalesced 1-KiB wave loads.
  float acc = 0.0f;
  for (long long i = tid; i < n4; i += stride) {
    float4 v = x4[i];
    float s = 0.0f;
    s += (v.x != 0.0f) ? __logf(v.x) : 0.0f;
    s += (v.y != 0.0f) ? __logf(v.y) : 0.0f;
    s += (v.z != 0.0f) ? __logf(v.z) : 0.0f;
    s += (v.w != 0.0f) ? __logf(v.w) : 0.0f;
    acc += s;
  }

  // scalar tail (n % 4) — n = 4096*8192 so never runs; kept for generality.
  if (tid == 0) {
    for (long long j = n4 << 2; j < n; ++j) {
      float v = x[j];
      acc += (v != 0.0f) ? __logf(v) : 0.0f;
    }
  }

  // 64-lane wave butterfly (wave64!)
  #pragma unroll
  for (int off = 32; off > 0; off >>= 1) {
    acc += __shfl_down(acc, off, 64);
  }

  __shared__ float smem[4];  // 256 threads / 64 lanes = 4 waves
  const int lane = threadIdx.x & 63;
  const int wave = threadIdx.x >> 6;
  if (lane == 0) smem[wave] = acc;
  __syncthreads();

  if (threadIdx.x == 0) {
    // Plain coalesced-ish store, one per block. NO atomic, NO fence.
    partials[blockIdx.x] = (smem[0] + smem[1]) + (smem[2] + smem[3]);
  }
}

// One block reduces the NBLOCKS partials and writes the scalar output.
__global__ __launch_bounds__(256) void finalize_kernel(
    const float* __restrict__ partials, float* __restrict__ out,
    double mn_half) {
  float acc = 0.0f;
  for (int i = threadIdx.x; i < NBLOCKS; i += 256) acc += partials[i];

  #pragma unroll
  for (int off = 32; off > 0; off >>= 1) {
    acc += __shfl_down(acc, off, 64);
  }

  __shared__ float smem[4];
  const int lane = threadIdx.x & 63;
  const int wave = threadIdx.x >> 6;
  if (lane == 0) smem[wave] = acc;
  __syncthreads();

  if (threadIdx.x == 0) {
    float sumD = (smem[0] + smem[1]) + (smem[2] + smem[3]);
    double total = mn_half * LOG_2PI_PLUS_1 + 0.5 * (double)sumD;
    out[0] = (total > 0.0) ? (float)log1p(total) : 1.0f;
  }
}

extern "C" void kernel_launch(void* const* d_in, const int* in_sizes, int n_in,
                              void* d_out, int out_size, void* d_ws, size_t ws_size,
                              hipStream_t stream) {
  const float* x = (const float*)d_in[0];
  long long n = (long long)in_sizes[0];
  float* partials = (float*)d_ws;

  // No memset: every partials[0..NBLOCKS) slot is written by the main kernel.
  masked_logsum_kernel<<<NBLOCKS, 256, 0, stream>>>(x, n, partials);
  finalize_kernel<<<1, 256, 0, stream>>>(partials, (float*)d_out,
                                         0.5 * (double)n);
}